// Round 1
// baseline (144.937 us; speedup 1.0000x reference)
//
#include <hip/hip_runtime.h>

// Reck-mesh MZI layer, N=256, BATCH=4096.
// out[b][i] = sum_j x[b][j] * Re(e^{i phi_ext[i]} U[i][j])
// U built by 32640 sequential 2x2 row rotations; columns independent;
// wavefront t = 2L + p gives depth-509 schedule with disjoint row pairs per step.

#define NN    256
#define NMZ   32640
#define NB    4096
// ws layout: [0, 522240)          float4 coeffs (c, s*cos(phi), s*sin(phi), 0) per op
//            [524288, 786432)     Wt[256][256]  (Wt[j][i] = Re(e^{i phi_i} U[i][j]))
#define WS_WT_OFF 524288

__global__ __launch_bounds__(256) void coeff_kernel(const float* __restrict__ theta,
                                                    const float* __restrict__ phi,
                                                    float4* __restrict__ cf) {
    int k = blockIdx.x * 256 + threadIdx.x;
    if (k < NMZ) {
        float th = theta[k], ph = phi[k];
        float c = cosf(th), s = sinf(th);
        cf[k] = make_float4(c, s * cosf(ph), s * sinf(ph), 0.f);
    }
}

// Coefficients for op at wavefront step t, row position p.
// Active iff p <= t and p + t <= 508 (parity p==t mod 2 is structural).
// Inactive -> identity rotation (1,0,0) so the update is branchless.
__device__ __forceinline__ float4 fetch_coeff(const float4* __restrict__ cf, int t, int p) {
    float4 v = make_float4(1.f, 0.f, 0.f, 0.f);
    if ((p <= t) && (p + t <= 508)) {
        int L = (t - p) >> 1;                 // layer, 0..254
        int k = ((L * (511 - L)) >> 1) + p;   // off(L) = L*(511-L)/2
        v = cf[k];
    }
    return v;
}

// One 2x2 MZI rotation on complex pair (a = upper row, b = lower row).
// new_a = c*a - (sx - i sy)*b ;  new_b = (sx + i sy)*a + c*b
__device__ __forceinline__ void rot2(float& ar, float& ai, float& br, float& bi, float4 co) {
    float c = co.x, sx = co.y, sy = co.z;
    float nar = c * ar - (sx * br + sy * bi);
    float nai = c * ai - (sx * bi - sy * br);
    float nbr = sx * ar - sy * ai + c * br;
    float nbi = sx * ai + sy * ar + c * bi;
    ar = nar; ai = nai; br = nbr; bi = nbi;
}

// One wave (64 lanes) per column j of U. Lane l holds rows 4l..4l+3 in regs.
// Even t: ops p=4l, 4l+2 are intra-lane. Odd t: p=4l+1 intra-lane; p=4l+3
// crosses to lane l+1 (shfl); lane also finishes op p=4l-1 as the lower row
// using lane l-1's row 4l-1 and lane l-1's coeffs (shfl). No barriers, no LDS.
__global__ __launch_bounds__(64) void build_kernel(const float4* __restrict__ cf,
                                                   const float* __restrict__ phi_ext,
                                                   float* __restrict__ Wt) {
    const int j = blockIdx.x;   // column of U
    const int l = threadIdx.x;  // lane 0..63
    const int r0 = 4 * l;

    float ur0 = (r0 + 0 == j) ? 1.f : 0.f, ui0 = 0.f;
    float ur1 = (r0 + 1 == j) ? 1.f : 0.f, ui1 = 0.f;
    float ur2 = (r0 + 2 == j) ? 1.f : 0.f, ui2 = 0.f;
    float ur3 = (r0 + 3 == j) ? 1.f : 0.f, ui3 = 0.f;

    // 4-deep coefficient prefetch pipeline (static slot rotation via full unroll).
    float4 sA[4], sB[4];
#pragma unroll
    for (int jj = 0; jj < 4; ++jj) {
        int t = jj;
        int pA = (t & 1) ? (r0 + 1) : r0;
        sA[jj] = fetch_coeff(cf, t, pA);
        sB[jj] = fetch_coeff(cf, t, pA + 2);
    }

    for (int t0 = 0; t0 < 512; t0 += 4) {
#pragma unroll
        for (int jj = 0; jj < 4; ++jj) {
            const int t = t0 + jj;
            if ((jj & 1) == 0) {
                // even step: p = 4l (rows 4l,4l+1), p = 4l+2 (rows 4l+2,4l+3)
                rot2(ur0, ui0, ur1, ui1, sA[jj]);
                rot2(ur2, ui2, ur3, ui3, sB[jj]);
            } else {
                // shuffles read pre-step values (all before any state update)
                float d0r = __shfl_down(ur0, 1);      // lane l+1's row 4l+4
                float d0i = __shfl_down(ui0, 1);
                float u3r = __shfl_up(ur3, 1);        // lane l-1's row 4l-1
                float u3i = __shfl_up(ui3, 1);
                float cCx = __shfl_up(sB[jj].x, 1);   // lane l-1's coeffs for p=4l-1
                float cCy = __shfl_up(sB[jj].y, 1);
                float cCz = __shfl_up(sB[jj].z, 1);
                if (l == 0) { cCx = 1.f; cCy = 0.f; cCz = 0.f; }  // p=-1: identity

                // p = 4l+1: rows 4l+1,4l+2 intra-lane
                rot2(ur1, ui1, ur2, ui2, sA[jj]);

                // p = 4l+3: we are the upper row (4l+3), partner row from lane l+1
                float4 cb = sB[jj];
                float n3r = cb.x * ur3 - (cb.y * d0r + cb.z * d0i);
                float n3i = cb.x * ui3 - (cb.y * d0i - cb.z * d0r);

                // p = 4l-1: we are the lower row (4l), upper row from lane l-1
                float n0r = cCy * u3r - cCz * u3i + cCx * ur0;
                float n0i = cCy * u3i + cCz * u3r + cCx * ui0;

                ur3 = n3r; ui3 = n3i; ur0 = n0r; ui0 = n0i;
            }
            // prefetch coefficients for step t+4 into the slot just consumed
            {
                int tn = t + 4;
                int pA = (tn & 1) ? (r0 + 1) : r0;
                sA[jj] = fetch_coeff(cf, tn, pA);
                sB[jj] = fetch_coeff(cf, tn, pA + 2);
            }
        }
    }

    // phase screen + take real part; store transposed (Wt[j][i]) for coalescing
    float4 pe = *(const float4*)(phi_ext + r0);
    float w0 = cosf(pe.x) * ur0 - sinf(pe.x) * ui0;
    float w1 = cosf(pe.y) * ur1 - sinf(pe.y) * ui1;
    float w2 = cosf(pe.z) * ur2 - sinf(pe.z) * ui2;
    float w3 = cosf(pe.w) * ur3 - sinf(pe.w) * ui3;
    *(float4*)(Wt + j * NN + r0) = make_float4(w0, w1, w2, w3);
}

// out[4096][256] = x[4096][256] @ Wt[256][256]   (fp32, no fp32 MFMA on CDNA4)
// BM=64, BN=64, BK=32; 256 threads; 4x4 accumulators per thread.
__global__ __launch_bounds__(256) void gemm_kernel(const float* __restrict__ x,
                                                   const float* __restrict__ Wt,
                                                   float* __restrict__ out) {
    __shared__ float Xs[64][36];  // [m][k], rows 16B-aligned (36*4=144)
    __shared__ float Bs[32][68];  // [k][n], rows 16B-aligned (68*4=272)

    const int tid = threadIdx.x;
    const int b0 = blockIdx.x * 64;
    const int i0 = blockIdx.y * 64;
    const int tx = tid & 15;   // n-tile: 16 x 4
    const int ty = tid >> 4;   // m-tile: 16 x 4

    const int xr = tid >> 3;          // 0..31
    const int xc = (tid & 7) * 4;     // 0..28
    const int bk = tid >> 4;          // 0..15
    const int bc = (tid & 15) * 4;    // 0..60

    float acc[4][4] = {};

    for (int k0 = 0; k0 < NN; k0 += 32) {
        float4 g0 = *(const float4*)(x + (b0 + xr) * NN + k0 + xc);
        float4 g1 = *(const float4*)(x + (b0 + xr + 32) * NN + k0 + xc);
        float4 w0 = *(const float4*)(Wt + (k0 + bk) * NN + i0 + bc);
        float4 w1 = *(const float4*)(Wt + (k0 + bk + 16) * NN + i0 + bc);
        *(float4*)&Xs[xr][xc]      = g0;
        *(float4*)&Xs[xr + 32][xc] = g1;
        *(float4*)&Bs[bk][bc]      = w0;
        *(float4*)&Bs[bk + 16][bc] = w1;
        __syncthreads();

#pragma unroll 8
        for (int k = 0; k < 32; ++k) {
            float4 bv = *(const float4*)&Bs[k][tx * 4];
            float x0 = Xs[ty * 4 + 0][k];
            float x1 = Xs[ty * 4 + 1][k];
            float x2 = Xs[ty * 4 + 2][k];
            float x3 = Xs[ty * 4 + 3][k];
            acc[0][0] += x0 * bv.x; acc[0][1] += x0 * bv.y; acc[0][2] += x0 * bv.z; acc[0][3] += x0 * bv.w;
            acc[1][0] += x1 * bv.x; acc[1][1] += x1 * bv.y; acc[1][2] += x1 * bv.z; acc[1][3] += x1 * bv.w;
            acc[2][0] += x2 * bv.x; acc[2][1] += x2 * bv.y; acc[2][2] += x2 * bv.z; acc[2][3] += x2 * bv.w;
            acc[3][0] += x3 * bv.x; acc[3][1] += x3 * bv.y; acc[3][2] += x3 * bv.z; acc[3][3] += x3 * bv.w;
        }
        __syncthreads();
    }

#pragma unroll
    for (int mm = 0; mm < 4; ++mm) {
        *(float4*)(out + (b0 + ty * 4 + mm) * NN + i0 + tx * 4) =
            make_float4(acc[mm][0], acc[mm][1], acc[mm][2], acc[mm][3]);
    }
}

extern "C" void kernel_launch(void* const* d_in, const int* in_sizes, int n_in,
                              void* d_out, int out_size, void* d_ws, size_t ws_size,
                              hipStream_t stream) {
    const float* x     = (const float*)d_in[0];
    const float* theta = (const float*)d_in[1];
    const float* phi_i = (const float*)d_in[2];
    const float* phi_e = (const float*)d_in[3];
    float* out = (float*)d_out;

    float4* cf = (float4*)d_ws;                         // 32640 * 16B = 522240
    float*  Wt = (float*)((char*)d_ws + WS_WT_OFF);     // 256*256*4 = 262144

    coeff_kernel<<<dim3((NMZ + 255) / 256), dim3(256), 0, stream>>>(theta, phi_i, cf);
    build_kernel<<<dim3(NN), dim3(64), 0, stream>>>(cf, phi_e, Wt);
    gemm_kernel<<<dim3(NB / 64, NN / 64), dim3(256), 0, stream>>>(x, Wt, out);
}

// Round 2
// 89.480 us; speedup vs baseline: 1.6198x; 1.6198x over previous
//
#include <hip/hip_runtime.h>

// Reck-mesh MZI layer, N=256, BATCH=4096.
// out[b][i] = sum_j x[b][j] * Re(e^{i phi_ext[i]} U[i][j])
// Wavefront schedule t = 2L + p (depth 509, padded to 512): all ops at equal t
// touch disjoint row pairs. One wave per column; lane l holds rows 4l..4l+3.
// Coefficients pre-reordered into a (t,lane) stream with identities baked in.

#define NN 256
#define NB 4096
#define TSTRIDE 192                 // float4 per step: 3 slots * 64 lanes
#define NGRP_TAB 66                 // table covers t < 528 (loads overrun by 1 group)
#define WS_WT_OFF (528 * 192 * 16)  // 1,622,016 bytes; Wt[256][256] after the table

// ---------------- coefficient stream ----------------
// slot A: p = 4l (+1 if t odd);  slot B: p = A+2;  slot C (odd t): p = 4l-1
// (slot C = lane l-1's slot B, pre-shifted so the hot loop needs no coeff shuffle)
__global__ __launch_bounds__(64) void coeff2_kernel(const float* __restrict__ theta,
                                                    const float* __restrict__ phi,
                                                    float4* __restrict__ cf2) {
    const int t = blockIdx.x;
    const int l = threadIdx.x;
    const int pA = (t & 1) ? (4 * l + 1) : (4 * l);
    const int ps[3] = {pA, pA + 2, (t & 1) ? (4 * l - 1) : -1};
#pragma unroll
    for (int s = 0; s < 3; ++s) {
        int p = ps[s];
        float4 v = make_float4(1.f, 0.f, 0.f, 0.f);  // identity rotation
        if (p >= 0 && p <= t && p + t <= 508) {      // active op at (t,p)
            int L = (t - p) >> 1;                    // layer 0..254
            int k = ((L * (511 - L)) >> 1) + p;      // off(L) = L*(511-L)/2
            float th = theta[k], ph = phi[k];
            float c = cosf(th), sn = sinf(th);
            v = make_float4(c, sn * cosf(ph), sn * sinf(ph), 0.f);
        }
        cf2[t * TSTRIDE + s * 64 + l] = v;
    }
}

// ---------------- build U columns ----------------
__device__ __forceinline__ float dpp_up1(float x) {   // lane i <- lane i-1 (wave_shr1), lane0 -> 0
    int r = __builtin_amdgcn_update_dpp(0, __builtin_bit_cast(int, x), 0x138, 0xF, 0xF, true);
    return __builtin_bit_cast(float, r);
}
__device__ __forceinline__ float dpp_dn1(float x) {   // lane i <- lane i+1 (wave_shl1), lane63 -> 0
    int r = __builtin_amdgcn_update_dpp(0, __builtin_bit_cast(int, x), 0x130, 0xF, 0xF, true);
    return __builtin_bit_cast(float, r);
}

__device__ __forceinline__ void rot2(float& ar, float& ai, float& br, float& bi, float4 co) {
    float c = co.x, sx = co.y, sy = co.z;
    float nar = c * ar - (sx * br + sy * bi);
    float nai = c * ai - (sx * bi - sy * br);
    float nbr = sx * ar - sy * ai + c * br;
    float nbi = sx * ai + sy * ar + c * bi;
    ar = nar; ai = nai; br = nbr; bi = nbi;
}

__global__ __launch_bounds__(64, 1) void build_kernel(const float4* __restrict__ cf2,
                                                      const float* __restrict__ phi_ext,
                                                      float* __restrict__ Wt) {
    const int j = blockIdx.x;   // column of U
    const int l = threadIdx.x;  // lane
    const int r0 = 4 * l;

    float ur0 = (r0 + 0 == j) ? 1.f : 0.f, ui0 = 0.f;
    float ur1 = (r0 + 1 == j) ? 1.f : 0.f, ui1 = 0.f;
    float ur2 = (r0 + 2 == j) ? 1.f : 0.f, ui2 = 0.f;
    float ur3 = (r0 + 3 == j) ? 1.f : 0.f, ui3 = 0.f;

    float4 A0[8], B0[8], C0[4];
    float4 A1[8], B1[8], C1[4];
    const float4* base = cf2 + l;

    auto loadgrp = [&](int g, float4 (&A)[8], float4 (&B)[8], float4 (&C)[4]) {
        const float4* gp = base + (size_t)g * (8 * TSTRIDE);
#pragma unroll
        for (int jj = 0; jj < 8; ++jj) {
            A[jj] = gp[jj * TSTRIDE];
            B[jj] = gp[jj * TSTRIDE + 64];
        }
#pragma unroll
        for (int jj = 0; jj < 4; ++jj)
            C[jj] = gp[(2 * jj + 1) * TSTRIDE + 128];
    };

    auto compute = [&](float4 (&A)[8], float4 (&B)[8], float4 (&C)[4]) {
#pragma unroll
        for (int jj = 0; jj < 8; ++jj) {
            if ((jj & 1) == 0) {
                // even step: p=4l (rows 4l,4l+1), p=4l+2 (rows 4l+2,4l+3), intra-lane
                rot2(ur0, ui0, ur1, ui1, A[jj]);
                rot2(ur2, ui2, ur3, ui3, B[jj]);
            } else {
                // DPP reads pre-step neighbor state (lockstep, before any write)
                float d0r = dpp_dn1(ur0), d0i = dpp_dn1(ui0);  // lane l+1's row 4l+4
                float u3r = dpp_up1(ur3), u3i = dpp_up1(ui3);  // lane l-1's row 4l-1
                // p = 4l+1: rows 4l+1,4l+2 intra-lane
                rot2(ur1, ui1, ur2, ui2, A[jj]);
                // p = 4l+3: we are upper row; partner from lane l+1 (lane63: B=identity)
                float4 cb = B[jj];
                float n3r = cb.x * ur3 - (cb.y * d0r + cb.z * d0i);
                float n3i = cb.x * ui3 - (cb.y * d0i - cb.z * d0r);
                // p = 4l-1: we are lower row; upper from lane l-1 (lane0: C=identity)
                float4 cc = C[jj >> 1];
                float n0r = cc.y * u3r - cc.z * u3i + cc.x * ur0;
                float n0i = cc.y * u3i + cc.z * u3r + cc.x * ui0;
                ur3 = n3r; ui3 = n3i; ur0 = n0r; ui0 = n0i;
            }
        }
    };

    loadgrp(0, A0, B0, C0);
    for (int g = 0; g < 64; g += 2) {   // 64 groups x 8 steps = 512 steps
        loadgrp(g + 1, A1, B1, C1);
        compute(A0, B0, C0);
        loadgrp(g + 2, A0, B0, C0);     // overruns into group 64 (identity pad, never computed)
        compute(A1, B1, C1);
    }

    // phase screen + real part; store transposed (Wt[j][i]) for coalesced GEMM reads
    float4 pe = *(const float4*)(phi_ext + r0);
    float w0 = cosf(pe.x) * ur0 - sinf(pe.x) * ui0;
    float w1 = cosf(pe.y) * ur1 - sinf(pe.y) * ui1;
    float w2 = cosf(pe.z) * ur2 - sinf(pe.z) * ui2;
    float w3 = cosf(pe.w) * ur3 - sinf(pe.w) * ui3;
    *(float4*)(Wt + j * NN + r0) = make_float4(w0, w1, w2, w3);
}

// ---------------- out = x @ Wt (fp32; no fp32 MFMA on CDNA4) ----------------
__global__ __launch_bounds__(256) void gemm_kernel(const float* __restrict__ x,
                                                   const float* __restrict__ Wt,
                                                   float* __restrict__ out) {
    __shared__ float Xs[64][36];
    __shared__ float Bs[32][68];

    const int tid = threadIdx.x;
    const int b0 = blockIdx.x * 64;
    const int i0 = blockIdx.y * 64;
    const int tx = tid & 15;
    const int ty = tid >> 4;

    const int xr = tid >> 3;
    const int xc = (tid & 7) * 4;
    const int bk = tid >> 4;
    const int bc = (tid & 15) * 4;

    float acc[4][4] = {};

    for (int k0 = 0; k0 < NN; k0 += 32) {
        float4 g0 = *(const float4*)(x + (b0 + xr) * NN + k0 + xc);
        float4 g1 = *(const float4*)(x + (b0 + xr + 32) * NN + k0 + xc);
        float4 w0 = *(const float4*)(Wt + (k0 + bk) * NN + i0 + bc);
        float4 w1 = *(const float4*)(Wt + (k0 + bk + 16) * NN + i0 + bc);
        *(float4*)&Xs[xr][xc]      = g0;
        *(float4*)&Xs[xr + 32][xc] = g1;
        *(float4*)&Bs[bk][bc]      = w0;
        *(float4*)&Bs[bk + 16][bc] = w1;
        __syncthreads();

#pragma unroll 8
        for (int k = 0; k < 32; ++k) {
            float4 bv = *(const float4*)&Bs[k][tx * 4];
            float x0 = Xs[ty * 4 + 0][k];
            float x1 = Xs[ty * 4 + 1][k];
            float x2 = Xs[ty * 4 + 2][k];
            float x3 = Xs[ty * 4 + 3][k];
            acc[0][0] += x0 * bv.x; acc[0][1] += x0 * bv.y; acc[0][2] += x0 * bv.z; acc[0][3] += x0 * bv.w;
            acc[1][0] += x1 * bv.x; acc[1][1] += x1 * bv.y; acc[1][2] += x1 * bv.z; acc[1][3] += x1 * bv.w;
            acc[2][0] += x2 * bv.x; acc[2][1] += x2 * bv.y; acc[2][2] += x2 * bv.z; acc[2][3] += x2 * bv.w;
            acc[3][0] += x3 * bv.x; acc[3][1] += x3 * bv.y; acc[3][2] += x3 * bv.z; acc[3][3] += x3 * bv.w;
        }
        __syncthreads();
    }

#pragma unroll
    for (int mm = 0; mm < 4; ++mm) {
        *(float4*)(out + (b0 + ty * 4 + mm) * NN + i0 + tx * 4) =
            make_float4(acc[mm][0], acc[mm][1], acc[mm][2], acc[mm][3]);
    }
}

extern "C" void kernel_launch(void* const* d_in, const int* in_sizes, int n_in,
                              void* d_out, int out_size, void* d_ws, size_t ws_size,
                              hipStream_t stream) {
    const float* x     = (const float*)d_in[0];
    const float* theta = (const float*)d_in[1];
    const float* phi_i = (const float*)d_in[2];
    const float* phi_e = (const float*)d_in[3];
    float* out = (float*)d_out;

    float4* cf2 = (float4*)d_ws;                       // 528*192*16 = 1,622,016 B
    float*  Wt  = (float*)((char*)d_ws + WS_WT_OFF);   // 256*256*4  =   262,144 B

    coeff2_kernel<<<dim3(528), dim3(64), 0, stream>>>(theta, phi_i, cf2);
    build_kernel<<<dim3(NN), dim3(64), 0, stream>>>(cf2, phi_e, Wt);
    gemm_kernel<<<dim3(NB / 64, NN / 64), dim3(256), 0, stream>>>(x, Wt, out);
}